// Round 4
// baseline (1431.216 us; speedup 1.0000x reference)
//
#include <hip/hip_runtime.h>
#include <hip/hip_bf16.h>

#define N_NODES 50000
#define D_FEAT  256
#define G_GROUPS 4
#define E_EDGES 800000
#define DG      64
#define TOT_E   (G_GROUPS * E_EDGES)        // 3200000 edges
#define M_PAD   50048                       // 391 * 128
#define RB_LOG  7                           // 128 rows per bucket
#define RB_SZ   128
#define NB_PG   391                         // row-blocks per group (391*128 = 50048)
#define NBK     (G_GROUPS * NB_PG)          // 1564 buckets
#define EPB     16384                       // edges per partition block
#define NPB     196                         // ceil(TOT_E / EPB)

typedef short bf16x8 __attribute__((ext_vector_type(8)));
typedef float f32x4  __attribute__((ext_vector_type(4)));

__device__ __forceinline__ unsigned short f2bf(float f) {
    unsigned int u = __float_as_uint(f);
    u += 0x7FFF + ((u >> 16) & 1);          // RNE
    return (unsigned short)(u >> 16);
}
__device__ __forceinline__ float bf2f(unsigned short h) {
    return __uint_as_float((unsigned int)h << 16);
}

// ---------------------------------------------------------------------------
// converts
// ---------------------------------------------------------------------------
__global__ __launch_bounds__(256) void convert_x_kernel(
    const float* __restrict__ x, unsigned short* __restrict__ xb)
{
    const long long base = ((long long)blockIdx.x * 256 + threadIdx.x) * 8;
    if (base >= (long long)N_NODES * D_FEAT) return;
    const float4 v0 = *(const float4*)&x[base];
    const float4 v1 = *(const float4*)&x[base + 4];
    unsigned short r[8];
    r[0] = f2bf(v0.x); r[1] = f2bf(v0.y); r[2] = f2bf(v0.z); r[3] = f2bf(v0.w);
    r[4] = f2bf(v1.x); r[5] = f2bf(v1.y); r[6] = f2bf(v1.z); r[7] = f2bf(v1.w);
    *(uint4*)&xb[base] = *(const uint4*)r;
}

__global__ __launch_bounds__(256) void convert_w_kernel(
    const float* __restrict__ W, unsigned short* __restrict__ Wt)
{
    const int n = blockIdx.x;
    const int k = threadIdx.x;
    Wt[n * D_FEAT + k] = f2bf(W[k * D_FEAT + n]);
}

// ---------------------------------------------------------------------------
// P1: exact bucket histogram, LDS-privatized.
// ---------------------------------------------------------------------------
__global__ __launch_bounds__(256) void hist_kernel(
    const int* __restrict__ edge_row, int* __restrict__ hist)
{
    __shared__ int h[NBK];
    const int tid = threadIdx.x;
    for (int k = tid; k < NBK; k += 256) h[k] = 0;
    __syncthreads();
    #pragma unroll
    for (int k = 0; k < EPB / 1024; ++k) {                  // 16 int4 per thread
        const int c = blockIdx.x * (EPB / 4) + k * 256 + tid;
        const long long i = (long long)c * 4;
        if (i >= TOT_E) continue;
        const int4 r = ((const int4*)edge_row)[c];
        const int g = (int)(i / E_EDGES);                   // E divisible by 4
        atomicAdd(&h[g * NB_PG + (r.x >> RB_LOG)], 1);
        atomicAdd(&h[g * NB_PG + (r.y >> RB_LOG)], 1);
        atomicAdd(&h[g * NB_PG + (r.z >> RB_LOG)], 1);
        atomicAdd(&h[g * NB_PG + (r.w >> RB_LOG)], 1);
    }
    __syncthreads();
    for (int k = tid; k < NBK; k += 256)
        if (h[k]) atomicAdd(&hist[k], h[k]);
}

// ---------------------------------------------------------------------------
// P2: exclusive scan of 1564 counters (single block), writes offs + cursor.
// ---------------------------------------------------------------------------
__global__ __launch_bounds__(256) void scan_kernel(
    const int* __restrict__ hist, int* __restrict__ offs, int* __restrict__ cursor)
{
    __shared__ int part[256];
    const int t = threadIdx.x;
    int local[7];
    int s = 0;
    #pragma unroll
    for (int k = 0; k < 7; ++k) {
        const int idx = t * 7 + k;
        local[k] = s;
        s += (idx < NBK) ? hist[idx] : 0;
    }
    part[t] = s;
    __syncthreads();
    for (int off = 1; off < 256; off <<= 1) {
        const int v = (t >= off) ? part[t - off] : 0;
        __syncthreads();
        part[t] += v;
        __syncthreads();
    }
    const int excl = part[t] - s;
    #pragma unroll
    for (int k = 0; k < 7; ++k) {
        const int idx = t * 7 + k;
        if (idx < NBK) { offs[idx] = excl + local[k]; cursor[idx] = excl + local[k]; }
    }
    if (t == 255) offs[NBK] = part[255];
}

// ---------------------------------------------------------------------------
// P3: block-aggregated scatter into bucket-packed 8B records.
// rec = { (row_local << 16) | col , f32 val }
// ---------------------------------------------------------------------------
__global__ __launch_bounds__(256) void scatter_kernel(
    const int* __restrict__ edge_row, const int* __restrict__ edge_col,
    const float* __restrict__ edge_val, int* __restrict__ cursor,
    uint2* __restrict__ recs)
{
    __shared__ int lh[NBK];
    const int tid = threadIdx.x;
    for (int k = tid; k < NBK; k += 256) lh[k] = 0;
    __syncthreads();
    // pass 1: local counts
    #pragma unroll
    for (int k = 0; k < EPB / 1024; ++k) {
        const int c = blockIdx.x * (EPB / 4) + k * 256 + tid;
        const long long i = (long long)c * 4;
        if (i >= TOT_E) continue;
        const int4 r = ((const int4*)edge_row)[c];
        const int g = (int)(i / E_EDGES);
        atomicAdd(&lh[g * NB_PG + (r.x >> RB_LOG)], 1);
        atomicAdd(&lh[g * NB_PG + (r.y >> RB_LOG)], 1);
        atomicAdd(&lh[g * NB_PG + (r.z >> RB_LOG)], 1);
        atomicAdd(&lh[g * NB_PG + (r.w >> RB_LOG)], 1);
    }
    __syncthreads();
    // reserve global runs; lh[k] becomes this block's running cursor
    for (int k = tid; k < NBK; k += 256) {
        const int n = lh[k];
        if (n) lh[k] = atomicAdd(&cursor[k], n);
    }
    __syncthreads();
    // pass 2: place records
    #pragma unroll
    for (int k = 0; k < EPB / 1024; ++k) {
        const int c = blockIdx.x * (EPB / 4) + k * 256 + tid;
        const long long i = (long long)c * 4;
        if (i >= TOT_E) continue;
        const int4 r = ((const int4*)edge_row)[c];
        const int4 cc = ((const int4*)edge_col)[c];
        const float4 vv = ((const float4*)edge_val)[c];
        const int g = (int)(i / E_EDGES);
        int b, pos;
        b = g * NB_PG + (r.x >> RB_LOG); pos = atomicAdd(&lh[b], 1);
        recs[pos] = make_uint2(((unsigned)(r.x & (RB_SZ - 1)) << 16) | (unsigned)cc.x, __float_as_uint(vv.x));
        b = g * NB_PG + (r.y >> RB_LOG); pos = atomicAdd(&lh[b], 1);
        recs[pos] = make_uint2(((unsigned)(r.y & (RB_SZ - 1)) << 16) | (unsigned)cc.y, __float_as_uint(vv.y));
        b = g * NB_PG + (r.z >> RB_LOG); pos = atomicAdd(&lh[b], 1);
        recs[pos] = make_uint2(((unsigned)(r.z & (RB_SZ - 1)) << 16) | (unsigned)cc.z, __float_as_uint(vv.z));
        b = g * NB_PG + (r.w >> RB_LOG); pos = atomicAdd(&lh[b], 1);
        recs[pos] = make_uint2(((unsigned)(r.w & (RB_SZ - 1)) << 16) | (unsigned)cc.w, __float_as_uint(vv.w));
    }
}

// ---------------------------------------------------------------------------
// SpMM: one block per bucket. 128x64 f32 LDS accumulator; waves stream the
// bucket's records (wave-uniform 8B loads), gather 128B of bf16 x, ds_add_f32.
// ---------------------------------------------------------------------------
__global__ __launch_bounds__(256) void spmm_bucket_kernel(
    const unsigned short* __restrict__ xb, const uint2* __restrict__ recs,
    const int* __restrict__ offs, unsigned short* __restrict__ tmpb)
{
    __shared__ float accs[RB_SZ * DG];      // 32 KB
    const int b = blockIdx.x;
    const int g = b / NB_PG, rb = b - g * NB_PG;
    const int tid = threadIdx.x, wid = tid >> 6, lane = tid & 63;

    #pragma unroll
    for (int k = 0; k < RB_SZ * DG / 256; ++k)
        accs[k * 256 + tid] = 0.f;
    __syncthreads();

    const int start = offs[b], end = offs[b + 1];
    const unsigned short* __restrict__ xcol = xb + g * DG + lane;

    for (int e = start + wid; e < end; e += 4) {
        const uint2 rec = recs[e];                       // wave-uniform
        const int col = rec.x & 0xFFFF;
        const int rl  = rec.x >> 16;
        const float val = __uint_as_float(rec.y);
        atomicAdd(&accs[rl * DG + lane], val * bf2f(xcol[(long long)col * D_FEAT]));
    }
    __syncthreads();

    const int row0 = rb * RB_SZ;
    #pragma unroll
    for (int l = 0; l < 4; ++l) {
        const int c = tid + l * 256;                     // chunk of 8 ushorts
        const int r = c >> 3, off = (c & 7) * 8;
        unsigned short o[8];
        #pragma unroll
        for (int j = 0; j < 8; ++j) o[j] = f2bf(accs[r * DG + off + j]);
        *(uint4*)&tmpb[(long long)(row0 + r) * D_FEAT + g * DG + off] = *(const uint4*)o;
    }
}

// ---------------------------------------------------------------------------
// MFMA GEMM: C[M,256] = tmp_bf @ W + bias (unchanged from round 3)
// ---------------------------------------------------------------------------
#define TBK 32
#define LDP 40

__global__ __launch_bounds__(256) void gemm_mfma_kernel(
    const unsigned short* __restrict__ A, const unsigned short* __restrict__ Bt,
    const float* __restrict__ bias, float* __restrict__ C)
{
    __shared__ unsigned short As[128][LDP];
    __shared__ unsigned short Bs[128][LDP];

    const int tid = threadIdx.x;
    const int wid = tid >> 6, lane = tid & 63;
    const int wm = (wid & 1) * 64, wn = (wid >> 1) * 64;
    const int lm = lane & 15, lq = lane >> 4;
    const int row0 = blockIdx.x * 128, col0 = blockIdx.y * 128;

    f32x4 acc[4][4] = {};

    for (int k0 = 0; k0 < D_FEAT; k0 += TBK) {
        #pragma unroll
        for (int l = 0; l < 2; ++l) {
            const int chunk = tid + l * 256;
            const int r = chunk >> 2;
            const int c = (chunk & 3) * 8;
            uint4 v = make_uint4(0u, 0u, 0u, 0u);
            const int gr = row0 + r;
            if (gr < N_NODES)
                v = *(const uint4*)&A[(long long)gr * D_FEAT + k0 + c];
            *(uint4*)&As[r][c] = v;
        }
        #pragma unroll
        for (int l = 0; l < 2; ++l) {
            const int chunk = tid + l * 256;
            const int r = chunk >> 2;
            const int c = (chunk & 3) * 8;
            *(uint4*)&Bs[r][c] =
                *(const uint4*)&Bt[(long long)(col0 + r) * D_FEAT + k0 + c];
        }
        __syncthreads();

        bf16x8 af[4], bfr[4];
        #pragma unroll
        for (int mi = 0; mi < 4; ++mi)
            af[mi] = *(const bf16x8*)&As[wm + mi * 16 + lm][lq * 8];
        #pragma unroll
        for (int ni = 0; ni < 4; ++ni)
            bfr[ni] = *(const bf16x8*)&Bs[wn + ni * 16 + lm][lq * 8];
        #pragma unroll
        for (int mi = 0; mi < 4; ++mi)
            #pragma unroll
            for (int ni = 0; ni < 4; ++ni)
                acc[mi][ni] = __builtin_amdgcn_mfma_f32_16x16x32_bf16(
                    af[mi], bfr[ni], acc[mi][ni], 0, 0, 0);
        __syncthreads();
    }

    #pragma unroll
    for (int mi = 0; mi < 4; ++mi) {
        #pragma unroll
        for (int ni = 0; ni < 4; ++ni) {
            const int n = col0 + wn + ni * 16 + lm;
            const float bv = bias[n];
            #pragma unroll
            for (int r = 0; r < 4; ++r) {
                const int m = row0 + wm + mi * 16 + lq * 4 + r;
                if (m < N_NODES)
                    C[(long long)m * D_FEAT + n] = acc[mi][ni][r] + bv;
            }
        }
    }
}

// ---------------------------------------------------------------------------
// Fallback (atomic f32 path) — only if ws too small.
// ---------------------------------------------------------------------------
__global__ __launch_bounds__(256) void spmm_scatter_kernel(
    const float* __restrict__ x, const int* __restrict__ edge_row,
    const int* __restrict__ edge_col, const float* __restrict__ edge_val,
    float* __restrict__ tmp)
{
    const long long gtid = (long long)blockIdx.x * blockDim.x + threadIdx.x;
    const int wave = (int)(gtid >> 6);
    const int lane = threadIdx.x & 63;
    if (wave >= TOT_E) return;
    const int g = wave / E_EDGES;
    const int row = edge_row[wave];
    const int col = edge_col[wave];
    const float val = edge_val[wave];
    atomicAdd(&tmp[(long long)row * D_FEAT + g * DG + lane],
              val * x[(long long)col * D_FEAT + g * DG + lane]);
}

__global__ __launch_bounds__(256) void gemm_bias_kernel(
    const float* __restrict__ A, const float* __restrict__ W,
    const float* __restrict__ bias, float* __restrict__ C)
{
    __shared__ float Asf[64][68];
    __shared__ float Wsf[64][68];
    const int tid = threadIdx.x;
    const int tx = tid & 15, ty = tid >> 4;
    const int row0 = blockIdx.x * 64, col0 = blockIdx.y * 64;
    float acc[4][4] = {};
    for (int k0 = 0; k0 < D_FEAT; k0 += 64) {
        #pragma unroll
        for (int l = 0; l < 4; ++l) {
            const int linear = tid + l * 256;
            const int ar = linear >> 4, ac = (linear & 15) << 2;
            float4 v = make_float4(0.f, 0.f, 0.f, 0.f);
            const int gr = row0 + ar;
            if (gr < N_NODES) v = *(const float4*)&A[(long long)gr * D_FEAT + k0 + ac];
            Asf[ac + 0][ar] = v.x; Asf[ac + 1][ar] = v.y;
            Asf[ac + 2][ar] = v.z; Asf[ac + 3][ar] = v.w;
        }
        #pragma unroll
        for (int l = 0; l < 4; ++l) {
            const int linear = tid + l * 256;
            const int wr = linear >> 4, wc = (linear & 15) << 2;
            *(float4*)&Wsf[wr][wc] =
                *(const float4*)&W[(long long)(k0 + wr) * D_FEAT + col0 + wc];
        }
        __syncthreads();
        #pragma unroll
        for (int k = 0; k < 64; ++k) {
            const float4 a4 = *(const float4*)&Asf[k][ty * 4];
            const float4 b4 = *(const float4*)&Wsf[k][tx * 4];
            const float a[4] = {a4.x, a4.y, a4.z, a4.w};
            const float bb[4] = {b4.x, b4.y, b4.z, b4.w};
            #pragma unroll
            for (int i = 0; i < 4; ++i)
                #pragma unroll
                for (int j = 0; j < 4; ++j) acc[i][j] += a[i] * bb[j];
        }
        __syncthreads();
    }
    const float4 b4 = *(const float4*)&bias[col0 + tx * 4];
    #pragma unroll
    for (int i = 0; i < 4; ++i) {
        const int gr = row0 + ty * 4 + i;
        if (gr >= N_NODES) continue;
        float4 v;
        v.x = acc[i][0] + b4.x; v.y = acc[i][1] + b4.y;
        v.z = acc[i][2] + b4.z; v.w = acc[i][3] + b4.w;
        *(float4*)&C[(long long)gr * D_FEAT + col0 + tx * 4] = v;
    }
}

// ---------------------------------------------------------------------------
extern "C" void kernel_launch(void* const* d_in, const int* in_sizes, int n_in,
                              void* d_out, int out_size, void* d_ws, size_t ws_size,
                              hipStream_t stream)
{
    const float* x        = (const float*)d_in[0];
    const int*   edge_row = (const int*)d_in[1];
    const int*   edge_col = (const int*)d_in[2];
    const float* edge_val = (const float*)d_in[3];
    const float* weight   = (const float*)d_in[4];
    const float* bias     = (const float*)d_in[5];
    float* out = (float*)d_out;

    char* p = (char*)d_ws;
    auto alloc = [&](size_t bytes) {
        char* r = p;
        p += (bytes + 255) & ~(size_t)255;
        return r;
    };
    unsigned short* xb   = (unsigned short*)alloc((size_t)N_NODES * D_FEAT * 2); // 25.6 MB
    unsigned short* tmpb = (unsigned short*)alloc((size_t)M_PAD * D_FEAT * 2);   // 25.6 MB
    unsigned short* Wt   = (unsigned short*)alloc((size_t)D_FEAT * D_FEAT * 2);  // 128 KB
    uint2* recs = (uint2*)alloc((size_t)TOT_E * sizeof(uint2));                  // 25.6 MB
    int* hist   = (int*)  alloc((size_t)NBK * sizeof(int));
    int* offs   = (int*)  alloc((size_t)(NBK + 1) * sizeof(int));
    int* cursor = (int*)  alloc((size_t)NBK * sizeof(int));
    const size_t needed = (size_t)(p - (char*)d_ws);

    if (ws_size >= needed) {
        hipMemsetAsync(hist, 0, (size_t)NBK * sizeof(int), stream);
        convert_x_kernel<<<(N_NODES * D_FEAT / 8 + 255) / 256, 256, 0, stream>>>(x, xb);
        convert_w_kernel<<<D_FEAT, D_FEAT, 0, stream>>>(weight, Wt);
        hist_kernel<<<NPB, 256, 0, stream>>>(edge_row, hist);
        scan_kernel<<<1, 256, 0, stream>>>(hist, offs, cursor);
        scatter_kernel<<<NPB, 256, 0, stream>>>(edge_row, edge_col, edge_val, cursor, recs);
        spmm_bucket_kernel<<<NBK, 256, 0, stream>>>(xb, recs, offs, tmpb);
        dim3 grid(M_PAD / 128, D_FEAT / 128);
        gemm_mfma_kernel<<<grid, 256, 0, stream>>>(tmpb, Wt, bias, out);
    } else {
        float* tmp = (float*)d_ws;
        hipMemsetAsync(tmp, 0, (size_t)N_NODES * D_FEAT * sizeof(float), stream);
        const long long total_threads = (long long)TOT_E * 64;
        spmm_scatter_kernel<<<(int)((total_threads + 255) / 256), 256, 0, stream>>>(
            x, edge_row, edge_col, edge_val, tmp);
        dim3 grid2((N_NODES + 63) / 64, D_FEAT / 64);
        gemm_bias_kernel<<<grid2, 256, 0, stream>>>(tmp, weight, bias, out);
    }
}

// Round 6
// 1336.221 us; speedup vs baseline: 1.0711x; 1.0711x over previous
//
#include <hip/hip_runtime.h>
#include <hip/hip_bf16.h>

#define N_NODES 50000
#define D_FEAT  256
#define G_GROUPS 4
#define E_EDGES 800000
#define DG      64
#define TOT_E   (G_GROUPS * E_EDGES)        // 3200000 edges
#define M_PAD   50048                       // 782 * 64
#define RB_LOG  6                           // 64 rows per bucket
#define RB_SZ   64
#define NB_PG   782                         // row-blocks per group (782*64 = 50048)
#define NBK     (G_GROUPS * NB_PG)          // 3128 buckets
#define EPB     16384                       // edges per partition block
#define NPB     196                         // ceil(TOT_E / EPB)
#define SCAN_PT 13                          // scan items per thread (256*13 >= NBK)

typedef short bf16x8 __attribute__((ext_vector_type(8)));
typedef float f32x4  __attribute__((ext_vector_type(4)));

__device__ __forceinline__ unsigned short f2bf(float f) {
    unsigned int u = __float_as_uint(f);
    u += 0x7FFF + ((u >> 16) & 1);          // RNE
    return (unsigned short)(u >> 16);
}
__device__ __forceinline__ float bf2f(unsigned short h) {
    return __uint_as_float((unsigned int)h << 16);
}

// ---------------------------------------------------------------------------
// converts
// ---------------------------------------------------------------------------
__global__ __launch_bounds__(256) void convert_x_kernel(
    const float* __restrict__ x, unsigned short* __restrict__ xb)
{
    const long long base = ((long long)blockIdx.x * 256 + threadIdx.x) * 8;
    if (base >= (long long)N_NODES * D_FEAT) return;
    const float4 v0 = *(const float4*)&x[base];
    const float4 v1 = *(const float4*)&x[base + 4];
    unsigned short r[8];
    r[0] = f2bf(v0.x); r[1] = f2bf(v0.y); r[2] = f2bf(v0.z); r[3] = f2bf(v0.w);
    r[4] = f2bf(v1.x); r[5] = f2bf(v1.y); r[6] = f2bf(v1.z); r[7] = f2bf(v1.w);
    *(uint4*)&xb[base] = *(const uint4*)r;
}

__global__ __launch_bounds__(256) void convert_w_kernel(
    const float* __restrict__ W, unsigned short* __restrict__ Wt)
{
    const int n = blockIdx.x;
    const int k = threadIdx.x;
    Wt[n * D_FEAT + k] = f2bf(W[k * D_FEAT + n]);
}

// ---------------------------------------------------------------------------
// P1: exact bucket histogram, LDS-privatized.
// ---------------------------------------------------------------------------
__global__ __launch_bounds__(256) void hist_kernel(
    const int* __restrict__ edge_row, int* __restrict__ hist)
{
    __shared__ int h[NBK];
    const int tid = threadIdx.x;
    for (int k = tid; k < NBK; k += 256) h[k] = 0;
    __syncthreads();
    #pragma unroll
    for (int k = 0; k < EPB / 1024; ++k) {                  // 16 int4 per thread
        const int c = blockIdx.x * (EPB / 4) + k * 256 + tid;
        const long long i = (long long)c * 4;
        if (i >= TOT_E) continue;
        const int4 r = ((const int4*)edge_row)[c];
        const int g = (int)(i / E_EDGES);                   // E divisible by 4
        atomicAdd(&h[g * NB_PG + (r.x >> RB_LOG)], 1);
        atomicAdd(&h[g * NB_PG + (r.y >> RB_LOG)], 1);
        atomicAdd(&h[g * NB_PG + (r.z >> RB_LOG)], 1);
        atomicAdd(&h[g * NB_PG + (r.w >> RB_LOG)], 1);
    }
    __syncthreads();
    for (int k = tid; k < NBK; k += 256)
        if (h[k]) atomicAdd(&hist[k], h[k]);
}

// ---------------------------------------------------------------------------
// P2: exclusive scan with per-bucket starts padded up to multiples of 8
// records (so the SpMM's uint4 chunk loads are 16B-aligned).
// ---------------------------------------------------------------------------
__global__ __launch_bounds__(256) void scan_kernel(
    const int* __restrict__ hist, int* __restrict__ offs, int* __restrict__ cursor)
{
    __shared__ int part[256];
    const int t = threadIdx.x;
    int local[SCAN_PT];
    int s = 0;
    #pragma unroll
    for (int k = 0; k < SCAN_PT; ++k) {
        const int idx = t * SCAN_PT + k;
        local[k] = s;
        const int c = (idx < NBK) ? hist[idx] : 0;
        s += (c + 7) & ~7;                  // pad each bucket to 8-record mult
    }
    part[t] = s;
    __syncthreads();
    for (int off = 1; off < 256; off <<= 1) {
        const int v = (t >= off) ? part[t - off] : 0;
        __syncthreads();
        part[t] += v;
        __syncthreads();
    }
    const int excl = part[t] - s;
    #pragma unroll
    for (int k = 0; k < SCAN_PT; ++k) {
        const int idx = t * SCAN_PT + k;
        if (idx < NBK) { offs[idx] = excl + local[k]; cursor[idx] = excl + local[k]; }
    }
}

// ---------------------------------------------------------------------------
// P3: block-aggregated scatter into bucket-packed 8B records.
// rec = { (row_local << 16) | col , f32 val }
// ---------------------------------------------------------------------------
__global__ __launch_bounds__(256) void scatter_kernel(
    const int* __restrict__ edge_row, const int* __restrict__ edge_col,
    const float* __restrict__ edge_val, int* __restrict__ cursor,
    uint2* __restrict__ recs)
{
    __shared__ int lh[NBK];
    const int tid = threadIdx.x;
    for (int k = tid; k < NBK; k += 256) lh[k] = 0;
    __syncthreads();
    #pragma unroll
    for (int k = 0; k < EPB / 1024; ++k) {
        const int c = blockIdx.x * (EPB / 4) + k * 256 + tid;
        const long long i = (long long)c * 4;
        if (i >= TOT_E) continue;
        const int4 r = ((const int4*)edge_row)[c];
        const int g = (int)(i / E_EDGES);
        atomicAdd(&lh[g * NB_PG + (r.x >> RB_LOG)], 1);
        atomicAdd(&lh[g * NB_PG + (r.y >> RB_LOG)], 1);
        atomicAdd(&lh[g * NB_PG + (r.z >> RB_LOG)], 1);
        atomicAdd(&lh[g * NB_PG + (r.w >> RB_LOG)], 1);
    }
    __syncthreads();
    for (int k = tid; k < NBK; k += 256) {
        const int n = lh[k];
        if (n) lh[k] = atomicAdd(&cursor[k], n);
    }
    __syncthreads();
    #pragma unroll
    for (int k = 0; k < EPB / 1024; ++k) {
        const int c = blockIdx.x * (EPB / 4) + k * 256 + tid;
        const long long i = (long long)c * 4;
        if (i >= TOT_E) continue;
        const int4 r = ((const int4*)edge_row)[c];
        const int4 cc = ((const int4*)edge_col)[c];
        const float4 vv = ((const float4*)edge_val)[c];
        const int g = (int)(i / E_EDGES);
        int b, pos;
        b = g * NB_PG + (r.x >> RB_LOG); pos = atomicAdd(&lh[b], 1);
        recs[pos] = make_uint2(((unsigned)(r.x & (RB_SZ - 1)) << 16) | (unsigned)cc.x, __float_as_uint(vv.x));
        b = g * NB_PG + (r.y >> RB_LOG); pos = atomicAdd(&lh[b], 1);
        recs[pos] = make_uint2(((unsigned)(r.y & (RB_SZ - 1)) << 16) | (unsigned)cc.y, __float_as_uint(vv.y));
        b = g * NB_PG + (r.z >> RB_LOG); pos = atomicAdd(&lh[b], 1);
        recs[pos] = make_uint2(((unsigned)(r.z & (RB_SZ - 1)) << 16) | (unsigned)cc.z, __float_as_uint(vv.z));
        b = g * NB_PG + (r.w >> RB_LOG); pos = atomicAdd(&lh[b], 1);
        recs[pos] = make_uint2(((unsigned)(r.w & (RB_SZ - 1)) << 16) | (unsigned)cc.w, __float_as_uint(vv.w));
    }
}

// ---------------------------------------------------------------------------
// SpMM: one block per bucket (64 rows x 64 feats, 16KB LDS f32 accumulator).
// Each wave processes 8 records per iteration: 4 wave-uniform uint4 loads,
// then 8 INDEPENDENT x-gathers in flight, then 8 fma + ds_add.
// ---------------------------------------------------------------------------
__global__ __launch_bounds__(256) void spmm_bucket_kernel(
    const unsigned short* __restrict__ xb, const uint2* __restrict__ recs,
    const int* __restrict__ offs, const int* __restrict__ cnt,
    unsigned short* __restrict__ tmpb)
{
    __shared__ float accs[RB_SZ * DG];      // 16 KB
    const int b = blockIdx.x;
    const int g = b / NB_PG, rb = b - g * NB_PG;
    const int tid = threadIdx.x, wid = tid >> 6, lane = tid & 63;

    #pragma unroll
    for (int k = 0; k < RB_SZ * DG / 256; ++k)
        accs[k * 256 + tid] = 0.f;
    __syncthreads();

    const int start = offs[b];
    const int total = cnt[b];
    const int end = start + total;
    const int nch = total >> 3;             // full chunks of 8 records
    const unsigned short* __restrict__ xcol = xb + g * DG + lane;

    for (int c = wid; c < nch; c += 4) {
        const int e = start + c * 8;        // 8-record aligned (64B)
        const uint4 r0 = *(const uint4*)&recs[e + 0];
        const uint4 r1 = *(const uint4*)&recs[e + 2];
        const uint4 r2 = *(const uint4*)&recs[e + 4];
        const uint4 r3 = *(const uint4*)&recs[e + 6];
        const unsigned key[8] = {r0.x, r0.z, r1.x, r1.z, r2.x, r2.z, r3.x, r3.z};
        const unsigned vb [8] = {r0.y, r0.w, r1.y, r1.w, r2.y, r2.w, r3.y, r3.w};
        float xv[8];
        #pragma unroll
        for (int j = 0; j < 8; ++j)
            xv[j] = bf2f(xcol[(int)(key[j] & 0xFFFF) * D_FEAT]);
        #pragma unroll
        for (int j = 0; j < 8; ++j)
            atomicAdd(&accs[(int)(key[j] >> 16) * DG + lane],
                      __uint_as_float(vb[j]) * xv[j]);
    }
    // tail (<8 records), wave 0 only
    if (wid == 0) {
        for (int e = start + nch * 8; e < end; ++e) {
            const uint2 rec = recs[e];
            atomicAdd(&accs[(int)(rec.x >> 16) * DG + lane],
                      __uint_as_float(rec.y) * bf2f(xcol[(int)(rec.x & 0xFFFF) * D_FEAT]));
        }
    }
    __syncthreads();

    const int row0 = rb * RB_SZ;
    #pragma unroll
    for (int l = 0; l < 2; ++l) {
        const int c = tid + l * 256;                     // chunk of 8 ushorts
        const int r = c >> 3, off = (c & 7) * 8;
        unsigned short o[8];
        #pragma unroll
        for (int j = 0; j < 8; ++j) o[j] = f2bf(accs[r * DG + off + j]);
        *(uint4*)&tmpb[(long long)(row0 + r) * D_FEAT + g * DG + off] = *(const uint4*)o;
    }
}

// ---------------------------------------------------------------------------
// MFMA GEMM: C[M,256] = tmp_bf @ W + bias
// ---------------------------------------------------------------------------
#define TBK 32
#define LDP 40

__global__ __launch_bounds__(256) void gemm_mfma_kernel(
    const unsigned short* __restrict__ A, const unsigned short* __restrict__ Bt,
    const float* __restrict__ bias, float* __restrict__ C)
{
    __shared__ unsigned short As[128][LDP];
    __shared__ unsigned short Bs[128][LDP];

    const int tid = threadIdx.x;
    const int wid = tid >> 6, lane = tid & 63;
    const int wm = (wid & 1) * 64, wn = (wid >> 1) * 64;
    const int lm = lane & 15, lq = lane >> 4;
    const int row0 = blockIdx.x * 128, col0 = blockIdx.y * 128;

    f32x4 acc[4][4] = {};

    for (int k0 = 0; k0 < D_FEAT; k0 += TBK) {
        #pragma unroll
        for (int l = 0; l < 2; ++l) {
            const int chunk = tid + l * 256;
            const int r = chunk >> 2;
            const int c = (chunk & 3) * 8;
            uint4 v = make_uint4(0u, 0u, 0u, 0u);
            const int gr = row0 + r;
            if (gr < N_NODES)
                v = *(const uint4*)&A[(long long)gr * D_FEAT + k0 + c];
            *(uint4*)&As[r][c] = v;
        }
        #pragma unroll
        for (int l = 0; l < 2; ++l) {
            const int chunk = tid + l * 256;
            const int r = chunk >> 2;
            const int c = (chunk & 3) * 8;
            *(uint4*)&Bs[r][c] =
                *(const uint4*)&Bt[(long long)(col0 + r) * D_FEAT + k0 + c];
        }
        __syncthreads();

        bf16x8 af[4], bfr[4];
        #pragma unroll
        for (int mi = 0; mi < 4; ++mi)
            af[mi] = *(const bf16x8*)&As[wm + mi * 16 + lm][lq * 8];
        #pragma unroll
        for (int ni = 0; ni < 4; ++ni)
            bfr[ni] = *(const bf16x8*)&Bs[wn + ni * 16 + lm][lq * 8];
        #pragma unroll
        for (int mi = 0; mi < 4; ++mi)
            #pragma unroll
            for (int ni = 0; ni < 4; ++ni)
                acc[mi][ni] = __builtin_amdgcn_mfma_f32_16x16x32_bf16(
                    af[mi], bfr[ni], acc[mi][ni], 0, 0, 0);
        __syncthreads();
    }

    #pragma unroll
    for (int mi = 0; mi < 4; ++mi) {
        #pragma unroll
        for (int ni = 0; ni < 4; ++ni) {
            const int n = col0 + wn + ni * 16 + lm;
            const float bv = bias[n];
            #pragma unroll
            for (int r = 0; r < 4; ++r) {
                const int m = row0 + wm + mi * 16 + lq * 4 + r;
                if (m < N_NODES)
                    C[(long long)m * D_FEAT + n] = acc[mi][ni][r] + bv;
            }
        }
    }
}

// ---------------------------------------------------------------------------
// Fallback (atomic f32 path) — only if ws too small.
// ---------------------------------------------------------------------------
__global__ __launch_bounds__(256) void spmm_scatter_kernel(
    const float* __restrict__ x, const int* __restrict__ edge_row,
    const int* __restrict__ edge_col, const float* __restrict__ edge_val,
    float* __restrict__ tmp)
{
    const long long gtid = (long long)blockIdx.x * blockDim.x + threadIdx.x;
    const int wave = (int)(gtid >> 6);
    const int lane = threadIdx.x & 63;
    if (wave >= TOT_E) return;
    const int g = wave / E_EDGES;
    const int row = edge_row[wave];
    const int col = edge_col[wave];
    const float val = edge_val[wave];
    atomicAdd(&tmp[(long long)row * D_FEAT + g * DG + lane],
              val * x[(long long)col * D_FEAT + g * DG + lane]);
}

__global__ __launch_bounds__(256) void gemm_bias_kernel(
    const float* __restrict__ A, const float* __restrict__ W,
    const float* __restrict__ bias, float* __restrict__ C)
{
    __shared__ float Asf[64][68];
    __shared__ float Wsf[64][68];
    const int tid = threadIdx.x;
    const int tx = tid & 15, ty = tid >> 4;
    const int row0 = blockIdx.x * 64, col0 = blockIdx.y * 64;
    float acc[4][4] = {};
    for (int k0 = 0; k0 < D_FEAT; k0 += 64) {
        #pragma unroll
        for (int l = 0; l < 4; ++l) {
            const int linear = tid + l * 256;
            const int ar = linear >> 4, ac = (linear & 15) << 2;
            float4 v = make_float4(0.f, 0.f, 0.f, 0.f);
            const int gr = row0 + ar;
            if (gr < N_NODES) v = *(const float4*)&A[(long long)gr * D_FEAT + k0 + ac];
            Asf[ac + 0][ar] = v.x; Asf[ac + 1][ar] = v.y;
            Asf[ac + 2][ar] = v.z; Asf[ac + 3][ar] = v.w;
        }
        #pragma unroll
        for (int l = 0; l < 4; ++l) {
            const int linear = tid + l * 256;
            const int wr = linear >> 4, wc = (linear & 15) << 2;
            *(float4*)&Wsf[wr][wc] =
                *(const float4*)&W[(long long)(k0 + wr) * D_FEAT + col0 + wc];
        }
        __syncthreads();
        #pragma unroll
        for (int k = 0; k < 64; ++k) {
            const float4 a4 = *(const float4*)&Asf[k][ty * 4];
            const float4 b4 = *(const float4*)&Wsf[k][tx * 4];
            const float a[4] = {a4.x, a4.y, a4.z, a4.w};
            const float bb[4] = {b4.x, b4.y, b4.z, b4.w};
            #pragma unroll
            for (int i = 0; i < 4; ++i)
                #pragma unroll
                for (int j = 0; j < 4; ++j) acc[i][j] += a[i] * bb[j];
        }
        __syncthreads();
    }
    const float4 b4 = *(const float4*)&bias[col0 + tx * 4];
    #pragma unroll
    for (int i = 0; i < 4; ++i) {
        const int gr = row0 + ty * 4 + i;
        if (gr >= N_NODES) continue;
        float4 v;
        v.x = acc[i][0] + b4.x; v.y = acc[i][1] + b4.y;
        v.z = acc[i][2] + b4.z; v.w = acc[i][3] + b4.w;
        *(float4*)&C[(long long)gr * D_FEAT + col0 + tx * 4] = v;
    }
}

// ---------------------------------------------------------------------------
extern "C" void kernel_launch(void* const* d_in, const int* in_sizes, int n_in,
                              void* d_out, int out_size, void* d_ws, size_t ws_size,
                              hipStream_t stream)
{
    const float* x        = (const float*)d_in[0];
    const int*   edge_row = (const int*)d_in[1];
    const int*   edge_col = (const int*)d_in[2];
    const float* edge_val = (const float*)d_in[3];
    const float* weight   = (const float*)d_in[4];
    const float* bias     = (const float*)d_in[5];
    float* out = (float*)d_out;

    char* p = (char*)d_ws;
    auto alloc = [&](size_t bytes) {
        char* r = p;
        p += (bytes + 255) & ~(size_t)255;
        return r;
    };
    unsigned short* xb   = (unsigned short*)alloc((size_t)N_NODES * D_FEAT * 2); // 25.6 MB
    unsigned short* tmpb = (unsigned short*)alloc((size_t)M_PAD * D_FEAT * 2);   // 25.6 MB
    unsigned short* Wt   = (unsigned short*)alloc((size_t)D_FEAT * D_FEAT * 2);  // 128 KB
    uint2* recs = (uint2*)alloc(((size_t)TOT_E + 8 * NBK) * sizeof(uint2));      // 25.8 MB
    int* hist   = (int*)  alloc((size_t)NBK * sizeof(int));
    int* offs   = (int*)  alloc((size_t)NBK * sizeof(int));
    int* cursor = (int*)  alloc((size_t)NBK * sizeof(int));
    const size_t needed = (size_t)(p - (char*)d_ws);

    if (ws_size >= needed) {
        hipMemsetAsync(hist, 0, (size_t)NBK * sizeof(int), stream);
        convert_x_kernel<<<(N_NODES * D_FEAT / 8 + 255) / 256, 256, 0, stream>>>(x, xb);
        convert_w_kernel<<<D_FEAT, D_FEAT, 0, stream>>>(weight, Wt);
        hist_kernel<<<NPB, 256, 0, stream>>>(edge_row, hist);
        scan_kernel<<<1, 256, 0, stream>>>(hist, offs, cursor);
        scatter_kernel<<<NPB, 256, 0, stream>>>(edge_row, edge_col, edge_val, cursor, recs);
        spmm_bucket_kernel<<<NBK, 256, 0, stream>>>(xb, recs, offs, hist, tmpb);
        dim3 grid(M_PAD / 128, D_FEAT / 128);
        gemm_mfma_kernel<<<grid, 256, 0, stream>>>(tmpb, Wt, bias, out);
    } else {
        float* tmp = (float*)d_ws;
        hipMemsetAsync(tmp, 0, (size_t)N_NODES * D_FEAT * sizeof(float), stream);
        const long long total_threads = (long long)TOT_E * 64;
        spmm_scatter_kernel<<<(int)((total_threads + 255) / 256), 256, 0, stream>>>(
            x, edge_row, edge_col, edge_val, tmp);
        dim3 grid2((N_NODES + 63) / 64, D_FEAT / 64);
        gemm_bias_kernel<<<grid2, 256, 0, stream>>>(tmp, weight, bias, out);
    }
}